// Round 3
// baseline (253.163 us; speedup 1.0000x reference)
//
#include <hip/hip_runtime.h>
#include <hip/hip_bf16.h>

// Gathered skinny GEMM: out[b, r] = sum_d x[b,d] * w[indices[r], d]
//   x: [32][4096] f32, w: [11008][4096] f32, indices: [4403] i32,
//   out: [32][4403] f32
//
// R8: R7 (246us) fixed R6's atomic poison but halved occupancy (552 blocks =
// 2.2 waves/SIMD) -> latency-bound on the gathered-W stream, slice ~29us vs
// ~12us floor. VALU cvt work is negligible (~0.35us device-wide); occupancy
// is the whole ballgame for this gather.
// R8 = one kernel, full K per block, zero cross-block machinery:
//   - BLOCK=1024 (16 waves), grid = 276 r-tiles. Wave w owns the contiguous
//     256-float K-chunk w*256 (KSTEPS=8; same MFMA body as R5's p1).
//     4416 waves total, 16 waves/CU (4/SIMD) -- R5-level occupancy.
//     __launch_bounds__(1024) caps VGPR at 128 so the 16-wave block fits.
//   - 16 waves' partials tree-reduced via 32 KB LDS (conflict-free), then
//     plain masked scalar stores to out. No atomics, no memset, no partial
//     tensor, no p2. 276 blocks -> 20 CUs run a 2nd block: ~0.8us HBM tail.
// Floor: ~65-72 MB gathered W @ 6.3 TB/s ~= 11.5us; x f32 from L2
// (141 MB aggregate @ 34.5 TB/s) overlaps the HBM stream.
// MFMA layout (16x16x32 bf16, per m89/m91/m120):
//   A = gathered W rows: lane(quad=l>>4, m=l&15) reads
//       W[idx[rt*16+m]][k0 + s*32 + quad*8 + 0..7] (32 B contiguous), cvt bf16.
//   B = x rows b=m and b=m+16, same k-slice, cvt bf16.
//   D: lane holds D[r_local=quad*4+j][b=lane&15 (+16 for acc1)].

#define D_MODEL   4096
#define REMAINED  4403
#define BATCH     32
#define RT16      ((REMAINED + 15) / 16)  // 276 r-tiles
#define WAVES     16
#define KCHUNK    (D_MODEL / WAVES)       // 256 floats per wave
#define KSTEPS    (KCHUNK / 32)           // 8 MFMA k-steps per wave
#define BLOCK     (WAVES * 64)            // 1024
#define GRID1     RT16                    // 276 blocks

typedef __attribute__((ext_vector_type(8))) short  short8;   // 8 bf16
typedef __attribute__((ext_vector_type(4))) float  floatx4;  // 4 fp32 acc

union ABFrag { short8 s8; __hip_bfloat162 h2[4]; };

__device__ __forceinline__ short8 cvt8(const float4 a, const float4 b) {
    ABFrag f;
    f.h2[0] = __float22bfloat162_rn(make_float2(a.x, a.y));
    f.h2[1] = __float22bfloat162_rn(make_float2(a.z, a.w));
    f.h2[2] = __float22bfloat162_rn(make_float2(b.x, b.y));
    f.h2[3] = __float22bfloat162_rn(make_float2(b.z, b.w));
    return f.s8;
}

__global__ __launch_bounds__(BLOCK) void p1_mfma(
    const float* __restrict__ w,
    const int*   __restrict__ idx,
    const float* __restrict__ x,
    float*       __restrict__ out)
{
    const int warp = (int)threadIdx.x >> 6;
    const int lane = (int)threadIdx.x & 63;
    const int quad = lane >> 4;
    const int m    = lane & 15;

    const int rt = (int)blockIdx.x;
    const int k0 = warp * KCHUNK;          // this wave's K origin (floats)

    // gathered W row for this lane's A-fragment rows
    const int r   = rt * 16 + m;
    const int rc  = (r < REMAINED) ? r : (REMAINED - 1);  // padded rows: dup,
    const int row = idx[rc];                              // masked at the store

    // per step s: lane reads W[row][k0 + s*32 + quad*8 + 0..7]
    const float4* __restrict__ wp =
        (const float4*)(w + (size_t)row * D_MODEL + k0) + quad * 2;

    // B operands: x[b][same k-slice] as f32 (L2-resident), b = m and m+16
    const float4* __restrict__ xp0 =
        (const float4*)(x + (size_t)m * D_MODEL + k0) + quad * 2;
    const float4* __restrict__ xp1 =
        (const float4*)(x + (size_t)(m + 16) * D_MODEL + k0) + quad * 2;

    floatx4 acc0 = {0.f, 0.f, 0.f, 0.f};
    floatx4 acc1 = {0.f, 0.f, 0.f, 0.f};

#pragma unroll 2
    for (int s = 0; s < KSTEPS; ++s) {
        const float4 w0 = wp[s * 8 + 0];
        const float4 w1 = wp[s * 8 + 1];
        const float4 a0 = xp0[s * 8 + 0];
        const float4 a1 = xp0[s * 8 + 1];
        const float4 b0 = xp1[s * 8 + 0];
        const float4 b1 = xp1[s * 8 + 1];

        const short8 af = cvt8(w0, w1);
        const short8 x0 = cvt8(a0, a1);
        const short8 x1 = cvt8(b0, b1);

        acc0 = __builtin_amdgcn_mfma_f32_16x16x32_bf16(af, x0, acc0, 0, 0, 0);
        acc1 = __builtin_amdgcn_mfma_f32_16x16x32_bf16(af, x1, acc1, 0, 0, 0);
    }

    // ---- on-chip reduction of the 16 waves' k-partials -------------------
    // red[w][b*16 + r_local]; lane holds D[r_local=quad*4+j][b] for b=m, m+16
    __shared__ float red[WAVES][BATCH * 16];

    float4* lp = (float4*)red[warp];
    lp[m * 4 + quad]        = make_float4(acc0[0], acc0[1], acc0[2], acc0[3]);
    lp[(m + 16) * 4 + quad] = make_float4(acc1[0], acc1[1], acc1[2], acc1[3]);
    __syncthreads();

    // 512 outputs; threads 0..511 each sum 16 planes (stride-1 reads: free)
    const int e = (int)threadIdx.x;
    if (e < BATCH * 16) {
        float s = 0.f;
#pragma unroll
        for (int v = 0; v < WAVES; ++v) s += red[v][e];

        const int b  = e >> 4;
        const int rl = e & 15;
        const int rr = rt * 16 + rl;
        if (rr < REMAINED) out[(size_t)b * REMAINED + rr] = s;
    }
}

extern "C" void kernel_launch(void* const* d_in, const int* in_sizes, int n_in,
                              void* d_out, int out_size, void* d_ws, size_t ws_size,
                              hipStream_t stream) {
    const float* x   = (const float*)d_in[0];
    const float* w   = (const float*)d_in[1];
    const int*   idx = (const int*)d_in[2];
    float*       out = (float*)d_out;

    (void)d_ws; (void)ws_size;

    p1_mfma<<<GRID1, BLOCK, 0, stream>>>(w, idx, x, out);
}